// Round 15
// baseline (376.271 us; speedup 1.0000x reference)
//
#include <hip/hip_runtime.h>
#include <hip/hip_cooperative_groups.h>
#include <stdint.h>

namespace cg = cooperative_groups;

#define N_FEAT 32
#define NPB_SHIFT 8                   // 256 nodes per bin
#define NPB (1 << NPB_SHIFT)
#define MAX_BINS 512
#define BINSLOT 8192                  // fixed binstream slots per bin (avg load ~4096)
#define OVF_CAP 65536                 // overflow safety net (unused for this input)
#define PART_CHUNK 4096               // per-sub-chunk LDS cache in phase 1
#define FUSE_THREADS 1024
#define PART_THREADS 1024

// ---------- fallback 1: baseline atomic scatter (known-correct, ~177us) ----------
__global__ void zero_out(float* __restrict__ out, int n) {
    int i = blockIdx.x * blockDim.x + threadIdx.x;
    if (i < n) out[i] = 0.0f;
}

__global__ void mp_scatter_add(const float* __restrict__ x,
                               const int* __restrict__ src,
                               const int* __restrict__ dst,
                               float* __restrict__ out,
                               int n_edges) {
    long long tid = (long long)blockIdx.x * blockDim.x + threadIdx.x;
    long long total = (long long)n_edges * N_FEAT;
    if (tid >= total) return;
    int e = (int)(tid >> 5);
    int f = (int)(tid & 31);
    atomicAdd(&out[(long long)dst[e] * N_FEAT + f],
              x[(long long)src[e] * N_FEAT + f]);
}

// ---------- fallback 2: R13 3-kernel chain (known-correct, ~63us) ----------
__global__ void init_bins(int* __restrict__ bincur, int nbins,
                          int* __restrict__ ovf_cnt) {
    int t = blockIdx.x * blockDim.x + threadIdx.x;
    if (t < nbins) bincur[t] = t * BINSLOT;
    if (t == nbins) *ovf_cnt = 0;
}

__global__ void __launch_bounds__(PART_THREADS)
partition_bins(const int* __restrict__ src, const int* __restrict__ dst,
               int n_edges, int* __restrict__ bincur,
               uint32_t* __restrict__ binstream,
               uint32_t* __restrict__ ovf_src, uint32_t* __restrict__ ovf_dst,
               int* __restrict__ ovf_cnt, int nbins) {
    __shared__ uint32_t epack[PART_CHUNK];
    __shared__ uint16_t ebin[PART_CHUNK];
    __shared__ int cnt[MAX_BINS];
    __shared__ int base[MAX_BINS];
    const int beg = blockIdx.x * PART_CHUNK;
    const int end = min(beg + PART_CHUNK, n_edges);
    const int m = end - beg;

    for (int b = threadIdx.x; b < nbins; b += blockDim.x) cnt[b] = 0;
    __syncthreads();
    for (int i = threadIdx.x; i < m; i += blockDim.x) {
        int d = dst[beg + i];
        int s = src[beg + i];
        int b = d >> NPB_SHIFT;
        epack[i] = ((uint32_t)s << NPB_SHIFT) | (uint32_t)(d & (NPB - 1));
        ebin[i]  = (uint16_t)b;
        atomicAdd(&cnt[b], 1);
    }
    __syncthreads();
    for (int b = threadIdx.x; b < nbins; b += blockDim.x) {
        int c = cnt[b];
        base[b] = c ? atomicAdd(&bincur[b], c) : 0;
        cnt[b] = 0;
    }
    __syncthreads();
    for (int i = threadIdx.x; i < m; i += blockDim.x) {
        int b = ebin[i];
        uint32_t e = epack[i];
        int p = base[b] + atomicAdd(&cnt[b], 1);
        if (p < (b + 1) * BINSLOT) {
            binstream[p] = e;
        } else {
            int o = atomicAdd(ovf_cnt, 1);
            if (o < OVF_CAP) {
                ovf_src[o] = e >> NPB_SHIFT;
                ovf_dst[o] = ((uint32_t)b << NPB_SHIFT) | (e & (NPB - 1));
            }
        }
    }
}

__global__ void __launch_bounds__(FUSE_THREADS)
binsort_aggregate(const uint32_t* __restrict__ binstream,
                  const int* __restrict__ bincur,
                  const uint32_t* __restrict__ ovf_src,
                  const uint32_t* __restrict__ ovf_dst,
                  const int* __restrict__ ovf_cnt,
                  const float* __restrict__ x,
                  float* __restrict__ out, int n_nodes) {
    __shared__ uint32_t srtd[BINSLOT];
    __shared__ int hist[NPB];
    __shared__ int sc[NPB];
    __shared__ int lcur[NPB];
    const int b = blockIdx.x;
    const int n0 = b << NPB_SHIFT;
    const int nn = min(NPB, n_nodes - n0);
    const int binstart = b * BINSLOT;
    const int cnt = min(bincur[b] - binstart, BINSLOT);
    const int novf = *ovf_cnt;
    const int t = threadIdx.x;
    const int g  = t >> 5;
    const int l  = t & 31;
    const int e4 = l >> 3;
    const int q  = l & 7;
    const float4* __restrict__ x4 = (const float4*)x;
    float4* __restrict__ out4 = (float4*)out;

    if (t < NPB) { hist[t] = 0; lcur[t] = 0; }
    __syncthreads();
    for (int i = t; i < cnt; i += FUSE_THREADS)
        atomicAdd(&hist[binstream[binstart + i] & (NPB - 1)], 1);
    __syncthreads();
    int v = 0;
    if (t < NPB) { v = hist[t]; sc[t] = v; }
    __syncthreads();
    for (int off = 1; off < NPB; off <<= 1) {
        int u = 0;
        if (t < NPB && t >= off) u = sc[t - off];
        __syncthreads();
        if (t < NPB) sc[t] += u;
        __syncthreads();
    }
    if (t < NPB) hist[t] = sc[t] - v;
    __syncthreads();
    for (int i = t; i < cnt; i += FUSE_THREADS) {
        uint32_t e = binstream[binstart + i];
        int dl = (int)(e & (NPB - 1));
        int p = hist[dl] + atomicAdd(&lcur[dl], 1);
        srtd[p] = e >> NPB_SHIFT;
    }
    __syncthreads();

    for (int dl = g; dl < nn; dl += 32) {
        int beg = hist[dl];
        int end = sc[dl];
        float4 acc = make_float4(0.f, 0.f, 0.f, 0.f);
        for (int i = beg; i < end; i += 16) {
#pragma unroll
            for (int k = 0; k < 4; ++k) {
                int j = i + k * 4 + e4;
                bool ok = j < end;
                uint32_t s = srtd[ok ? j : i];
                float4 vv = x4[(size_t)s * (N_FEAT / 4) + q];
                float m = ok ? 1.0f : 0.0f;
                acc.x = fmaf(vv.x, m, acc.x);
                acc.y = fmaf(vv.y, m, acc.y);
                acc.z = fmaf(vv.z, m, acc.z);
                acc.w = fmaf(vv.w, m, acc.w);
            }
        }
        acc.x += __shfl_xor(acc.x, 8);  acc.y += __shfl_xor(acc.y, 8);
        acc.z += __shfl_xor(acc.z, 8);  acc.w += __shfl_xor(acc.w, 8);
        acc.x += __shfl_xor(acc.x, 16); acc.y += __shfl_xor(acc.y, 16);
        acc.z += __shfl_xor(acc.z, 16); acc.w += __shfl_xor(acc.w, 16);
        if (e4 == 0) {
            for (int i = 0; i < novf; ++i) {
                uint32_t od = ovf_dst[i];
                if ((int)(od >> NPB_SHIFT) == b && (int)(od & (NPB - 1)) == dl) {
                    float4 vv = x4[(size_t)ovf_src[i] * (N_FEAT / 4) + q];
                    acc.x += vv.x; acc.y += vv.y; acc.z += vv.z; acc.w += vv.w;
                }
            }
            out4[(size_t)(n0 + dl) * (N_FEAT / 4) + q] = acc;
        }
    }
}

// ---------- fast path: ONE cooperative kernel (R15) ----------
// Phase 0: init cursors (atomicExch -> coherence point). grid.sync().
// Phase 1: partition into fixed-capacity bins (LDS-cached chunk). fence+sync.
// Phase 2: per-bin LDS rank-sort (binstream read ONCE into ebuf) + register
//          aggregation + coalesced row stores.
__global__ void __launch_bounds__(FUSE_THREADS)
mp_fused(const int* __restrict__ src, const int* __restrict__ dst,
         int n_edges, int n_nodes, int nbins,
         int* __restrict__ bincur,
         uint32_t* __restrict__ binstream,
         uint32_t* __restrict__ ovf_src, uint32_t* __restrict__ ovf_dst,
         int* __restrict__ ovf_cnt,
         const float* __restrict__ x, float* __restrict__ out) {
    union U {
        struct { uint32_t epack[PART_CHUNK]; uint16_t ebin[PART_CHUNK]; } p1; // 24 KB
        struct { uint32_t ebuf[BINSLOT]; uint32_t srtd[BINSLOT]; } p2;        // 64 KB
    };
    __shared__ U sm;
    __shared__ int cnt[MAX_BINS];
    __shared__ int base[MAX_BINS];
    __shared__ int hist[NPB];
    __shared__ int sc[NPB];
    __shared__ int lcur[NPB];
    __shared__ int cnt_s, novf_s;

    const int t = threadIdx.x;
    cg::grid_group grid = cg::this_grid();

    // ---- phase 0: init ----
    if (t == 0) atomicExch(&bincur[blockIdx.x], blockIdx.x * BINSLOT);
    if (blockIdx.x == 0 && t == 1) atomicExch(ovf_cnt, 0);
    __threadfence();
    grid.sync();

    // ---- phase 1: partition ----
    {
        const int chunk = (n_edges + gridDim.x - 1) / gridDim.x;
        const int gbeg = blockIdx.x * chunk;
        const int gend = min(gbeg + chunk, n_edges);
        for (int sbeg = gbeg; sbeg < gend; sbeg += PART_CHUNK) {
            const int m = min(PART_CHUNK, gend - sbeg);
            for (int b = t; b < nbins; b += FUSE_THREADS) cnt[b] = 0;
            __syncthreads();
            for (int i = t; i < m; i += FUSE_THREADS) {
                int d = dst[sbeg + i];
                int s = src[sbeg + i];
                int b = d >> NPB_SHIFT;
                sm.p1.epack[i] = ((uint32_t)s << NPB_SHIFT) | (uint32_t)(d & (NPB - 1));
                sm.p1.ebin[i]  = (uint16_t)b;
                atomicAdd(&cnt[b], 1);               // LDS atomic
            }
            __syncthreads();
            for (int b = t; b < nbins; b += FUSE_THREADS) {
                int c = cnt[b];
                base[b] = c ? atomicAdd(&bincur[b], c) : 0;   // device-scope
                cnt[b] = 0;
            }
            __syncthreads();
            for (int i = t; i < m; i += FUSE_THREADS) {
                int b = sm.p1.ebin[i];
                uint32_t e = sm.p1.epack[i];
                int p = base[b] + atomicAdd(&cnt[b], 1);
                if (p < (b + 1) * BINSLOT) {
                    binstream[p] = e;
                } else {
                    int o = atomicAdd(ovf_cnt, 1);
                    if (o < OVF_CAP) {
                        ovf_src[o] = e >> NPB_SHIFT;
                        ovf_dst[o] = ((uint32_t)b << NPB_SHIFT) | (e & (NPB - 1));
                    }
                }
            }
            __syncthreads();
        }
    }
    __threadfence();
    grid.sync();

    // ---- phase 2: sort + aggregate, bin b = blockIdx.x ----
    {
        const int b = blockIdx.x;
        const int n0 = b << NPB_SHIFT;
        const int nn = min(NPB, n_nodes - n0);
        const int binstart = b * BINSLOT;
        if (t == 0) {
            cnt_s  = min(atomicAdd(&bincur[b], 0) - binstart, BINSLOT); // coherent read
            novf_s = atomicAdd(ovf_cnt, 0);
        }
        if (t < NPB) { hist[t] = 0; lcur[t] = 0; }
        __syncthreads();
        const int ec = cnt_s;
        const int novf = novf_s;
        const int g  = t >> 5;
        const int l  = t & 31;
        const int e4 = l >> 3;
        const int q  = l & 7;
        const float4* __restrict__ x4 = (const float4*)x;
        float4* __restrict__ out4 = (float4*)out;

        for (int i = t; i < ec; i += FUSE_THREADS) {
            uint32_t e = binstream[binstart + i];    // single global read
            sm.p2.ebuf[i] = e;
            atomicAdd(&hist[e & (NPB - 1)], 1);
        }
        __syncthreads();
        int v = 0;
        if (t < NPB) { v = hist[t]; sc[t] = v; }
        __syncthreads();
        for (int off = 1; off < NPB; off <<= 1) {
            int u = 0;
            if (t < NPB && t >= off) u = sc[t - off];
            __syncthreads();
            if (t < NPB) sc[t] += u;
            __syncthreads();
        }
        if (t < NPB) hist[t] = sc[t] - v;            // exclusive start
        __syncthreads();
        for (int i = t; i < ec; i += FUSE_THREADS) {
            uint32_t e = sm.p2.ebuf[i];              // LDS re-read (not global)
            int dl = (int)(e & (NPB - 1));
            int p = hist[dl] + atomicAdd(&lcur[dl], 1);
            sm.p2.srtd[p] = e >> NPB_SHIFT;
        }
        __syncthreads();

        for (int dl = g; dl < nn; dl += 32) {
            int beg = hist[dl];
            int end = sc[dl];
            float4 acc = make_float4(0.f, 0.f, 0.f, 0.f);
            for (int i = beg; i < end; i += 16) {
#pragma unroll
                for (int k = 0; k < 4; ++k) {
                    int j = i + k * 4 + e4;
                    bool ok = j < end;
                    uint32_t s = sm.p2.srtd[ok ? j : i];
                    float4 vv = x4[(size_t)s * (N_FEAT / 4) + q];
                    float m = ok ? 1.0f : 0.0f;
                    acc.x = fmaf(vv.x, m, acc.x);
                    acc.y = fmaf(vv.y, m, acc.y);
                    acc.z = fmaf(vv.z, m, acc.z);
                    acc.w = fmaf(vv.w, m, acc.w);
                }
            }
            acc.x += __shfl_xor(acc.x, 8);  acc.y += __shfl_xor(acc.y, 8);
            acc.z += __shfl_xor(acc.z, 8);  acc.w += __shfl_xor(acc.w, 8);
            acc.x += __shfl_xor(acc.x, 16); acc.y += __shfl_xor(acc.y, 16);
            acc.z += __shfl_xor(acc.z, 16); acc.w += __shfl_xor(acc.w, 16);
            if (e4 == 0) {
                for (int i = 0; i < novf; ++i) {     // novf==0 normally
                    uint32_t od = ovf_dst[i];
                    if ((int)(od >> NPB_SHIFT) == b && (int)(od & (NPB - 1)) == dl) {
                        float4 vv = x4[(size_t)ovf_src[i] * (N_FEAT / 4) + q];
                        acc.x += vv.x; acc.y += vv.y; acc.z += vv.z; acc.w += vv.w;
                    }
                }
                out4[(size_t)(n0 + dl) * (N_FEAT / 4) + q] = acc;
            }
        }
    }
}

extern "C" void kernel_launch(void* const* d_in, const int* in_sizes, int n_in,
                              void* d_out, int out_size, void* d_ws, size_t ws_size,
                              hipStream_t stream) {
    const float* x   = (const float*)d_in[0];
    const int*   ei  = (const int*)d_in[1];
    float*       out = (float*)d_out;

    const int n_edges = in_sizes[1] / 2;
    const int n_nodes = in_sizes[0] / N_FEAT;
    const int* src = ei;
    const int* dst = ei + n_edges;

    const int nbins = (n_nodes + NPB - 1) >> NPB_SHIFT;

    // workspace layout (same as R13)
    size_t off_binstream = 0;
    size_t off_ovf_src   = off_binstream + (size_t)nbins * BINSLOT * sizeof(uint32_t);
    size_t off_ovf_dst   = off_ovf_src + (size_t)OVF_CAP * sizeof(uint32_t);
    size_t off_bincur    = off_ovf_dst + (size_t)OVF_CAP * sizeof(uint32_t);
    size_t off_ovf_cnt   = off_bincur + (size_t)nbins * sizeof(int);
    size_t ws_needed     = off_ovf_cnt + sizeof(int);

    if (nbins > MAX_BINS || n_nodes > (1 << 23) || ws_size < ws_needed) {
        int threads = 256;
        zero_out<<<(out_size + threads - 1) / threads, threads, 0, stream>>>(out, out_size);
        long long total = (long long)n_edges * N_FEAT;
        mp_scatter_add<<<(int)((total + threads - 1) / threads), threads, 0, stream>>>(
            x, src, dst, out, n_edges);
        return;
    }

    char* ws = (char*)d_ws;
    uint32_t* binstream = (uint32_t*)(ws + off_binstream);
    uint32_t* ovf_src   = (uint32_t*)(ws + off_ovf_src);
    uint32_t* ovf_dst   = (uint32_t*)(ws + off_ovf_dst);
    int*      bincur    = (int*)(ws + off_bincur);
    int*      ovf_cnt   = (int*)(ws + off_ovf_cnt);

    // try the single cooperative kernel (391 blocks x 1024 thr; 2 blocks/CU)
    int ne = n_edges, nn = n_nodes, nb = nbins;
    void* args[] = { (void*)&src, (void*)&dst, (void*)&ne, (void*)&nn, (void*)&nb,
                     (void*)&bincur, (void*)&binstream, (void*)&ovf_src,
                     (void*)&ovf_dst, (void*)&ovf_cnt, (void*)&x, (void*)&out };
    hipError_t err = hipLaunchCooperativeKernel((const void*)mp_fused,
                                                dim3(nbins), dim3(FUSE_THREADS),
                                                args, 0, stream);
    if (err == hipSuccess) return;

    // fallback: proven R13 3-kernel chain
    init_bins<<<(nbins + 256) / 256, 256, 0, stream>>>(bincur, nbins, ovf_cnt);
    const int part_blocks = (n_edges + PART_CHUNK - 1) / PART_CHUNK;
    partition_bins<<<part_blocks, PART_THREADS, 0, stream>>>(
        src, dst, n_edges, bincur, binstream, ovf_src, ovf_dst, ovf_cnt, nbins);
    binsort_aggregate<<<nbins, FUSE_THREADS, 0, stream>>>(
        binstream, bincur, ovf_src, ovf_dst, ovf_cnt, x, out, n_nodes);
}

// Round 16
// 62.122 us; speedup vs baseline: 6.0570x; 6.0570x over previous
//
#include <hip/hip_runtime.h>
#include <stdint.h>

#define N_FEAT 32
#define NPB_SHIFT 8                   // 256 nodes per bin
#define NPB (1 << NPB_SHIFT)
#define MAX_BINS 512
#define BINSLOT 8192                  // fixed binstream slots per bin (avg load ~4096)
#define OVF_CAP 65536                 // overflow safety net (unused for this input)
#define PART_THREADS 1024
#define PART_CHUNK 3072               // edges per partition block (LDS-cached)
#define FUSE_THREADS 1024

// ---------- fallback path (baseline, known-correct, ~177us) ----------
__global__ void zero_out(float* __restrict__ out, int n) {
    int i = blockIdx.x * blockDim.x + threadIdx.x;
    if (i < n) out[i] = 0.0f;
}

__global__ void mp_scatter_add(const float* __restrict__ x,
                               const int* __restrict__ src,
                               const int* __restrict__ dst,
                               float* __restrict__ out,
                               int n_edges) {
    long long tid = (long long)blockIdx.x * blockDim.x + threadIdx.x;
    long long total = (long long)n_edges * N_FEAT;
    if (tid >= total) return;
    int e = (int)(tid >> 5);
    int f = (int)(tid & 31);
    atomicAdd(&out[(long long)dst[e] * N_FEAT + f],
              x[(long long)src[e] * N_FEAT + f]);
}

// ---------- fast path (R16 = R13 chain + ebuf single-read + wave-shfl scan) ----
// NOTE (R15 lesson): do NOT fuse these via cooperative grid.sync() — the
// grid-wide coherence requirement across non-coherent XCD L2s degraded all
// caching (376us vs 63us). Separate dispatches are the coherence points.

// K0: init per-bin cursors + overflow counter (ws is poisoned; must re-init).
__global__ void init_bins(int* __restrict__ bincur, int nbins,
                          int* __restrict__ ovf_cnt) {
    int t = blockIdx.x * blockDim.x + threadIdx.x;
    if (t < nbins) bincur[t] = t * BINSLOT;
    if (t == nbins) *ovf_cnt = 0;
}

// K1: partition edges into fixed-capacity bins (LDS-cached chunk; src/dst
// read from HBM exactly once).
__global__ void __launch_bounds__(PART_THREADS)
partition_bins(const int* __restrict__ src, const int* __restrict__ dst,
               int n_edges, int* __restrict__ bincur,
               uint32_t* __restrict__ binstream,
               uint32_t* __restrict__ ovf_src, uint32_t* __restrict__ ovf_dst,
               int* __restrict__ ovf_cnt, int nbins) {
    __shared__ uint32_t epack[PART_CHUNK];   // (src<<8)|dst_local
    __shared__ uint16_t ebin[PART_CHUNK];    // bin id
    __shared__ int cnt[MAX_BINS];
    __shared__ int base[MAX_BINS];
    const int beg = blockIdx.x * PART_CHUNK;
    const int end = min(beg + PART_CHUNK, n_edges);
    const int m = end - beg;

    for (int b = threadIdx.x; b < nbins; b += blockDim.x) cnt[b] = 0;
    __syncthreads();
    for (int i = threadIdx.x; i < m; i += blockDim.x) {
        int d = dst[beg + i];
        int s = src[beg + i];
        int b = d >> NPB_SHIFT;
        epack[i] = ((uint32_t)s << NPB_SHIFT) | (uint32_t)(d & (NPB - 1));
        ebin[i]  = (uint16_t)b;
        atomicAdd(&cnt[b], 1);               // LDS atomic
    }
    __syncthreads();
    for (int b = threadIdx.x; b < nbins; b += blockDim.x) {
        int c = cnt[b];
        base[b] = c ? atomicAdd(&bincur[b], c) : 0;   // one global atomic each
        cnt[b] = 0;                                   // becomes local cursor
    }
    __syncthreads();
    for (int i = threadIdx.x; i < m; i += blockDim.x) {
        int b = ebin[i];
        uint32_t e = epack[i];
        int p = base[b] + atomicAdd(&cnt[b], 1);      // LDS atomic
        if (p < (b + 1) * BINSLOT) {
            binstream[p] = e;                         // block-private segment
        } else {                                      // overflow net (never hit here)
            int o = atomicAdd(ovf_cnt, 1);
            if (o < OVF_CAP) {
                ovf_src[o] = e >> NPB_SHIFT;
                ovf_dst[o] = ((uint32_t)b << NPB_SHIFT) | (e & (NPB - 1));
            }
        }
    }
}

// K2 (FUSED sort+aggregate): one block per bin.
// R16a: binstream is read from global ONCE (staged in ebuf; placement pass
//       re-reads LDS).
// R16b: the 256-entry scan uses per-wave __shfl_up (64-wide) + a 4-entry
//       wave-total prefix -> 3 barriers instead of 16.
__global__ void __launch_bounds__(FUSE_THREADS)
binsort_aggregate(const uint32_t* __restrict__ binstream,
                  const int* __restrict__ bincur,
                  const uint32_t* __restrict__ ovf_src,
                  const uint32_t* __restrict__ ovf_dst,
                  const int* __restrict__ ovf_cnt,
                  const float* __restrict__ x,
                  float* __restrict__ out, int n_nodes) {
    __shared__ uint32_t ebuf[BINSLOT];     // 32 KB: raw bin edges (single global read)
    __shared__ uint32_t srtd[BINSLOT];     // 32 KB: rank-sorted src ids
    __shared__ int hist[NPB];              // counts -> exclusive per-node start
    __shared__ int sc[NPB];                // inclusive per-node end
    __shared__ int lcur[NPB];
    __shared__ int wsum[4];                // per-wave scan totals
    const int b = blockIdx.x;
    const int n0 = b << NPB_SHIFT;
    const int nn = min(NPB, n_nodes - n0);
    const int binstart = b * BINSLOT;
    const int cnt = min(bincur[b] - binstart, BINSLOT);
    const int novf = *ovf_cnt;             // 0 in practice
    const int t = threadIdx.x;
    const int g  = t >> 5;                 // group 0..31
    const int l  = t & 31;
    const int e4 = l >> 3;                 // edge slot 0..3
    const int q  = l & 7;                  // feature quad 0..7
    const float4* __restrict__ x4 = (const float4*)x;
    float4* __restrict__ out4 = (float4*)out;

    if (t < NPB) { hist[t] = 0; lcur[t] = 0; }
    __syncthreads();
    for (int i = t; i < cnt; i += FUSE_THREADS) {
        uint32_t e = binstream[binstart + i];          // single global read
        ebuf[i] = e;
        atomicAdd(&hist[e & (NPB - 1)], 1);
    }
    __syncthreads();

    // wave-shfl inclusive scan over hist[0..255] (4 full waves; guard is
    // wave-uniform since 256 = 4*64)
    int vin = 0, val = 0;
    if (t < NPB) {
        vin = hist[t];
        val = vin;
#pragma unroll
        for (int off = 1; off < 64; off <<= 1) {
            int u = __shfl_up(val, (unsigned)off, 64);
            if ((t & 63) >= off) val += u;
        }
        if ((t & 63) == 63) wsum[t >> 6] = val;
    }
    __syncthreads();
    if (t < NPB) {
        int w = t >> 6, prefix = 0;
#pragma unroll
        for (int k = 0; k < 3; ++k) if (k < w) prefix += wsum[k];
        val += prefix;
        sc[t] = val;                       // inclusive end
        hist[t] = val - vin;               // exclusive start
    }
    __syncthreads();

    for (int i = t; i < cnt; i += FUSE_THREADS) {
        uint32_t e = ebuf[i];              // LDS re-read (not global)
        int dl = (int)(e & (NPB - 1));
        int p = hist[dl] + atomicAdd(&lcur[dl], 1);
        srtd[p] = e >> NPB_SHIFT;          // src id
    }
    __syncthreads();

    for (int dl = g; dl < nn; dl += 32) {
        int beg = hist[dl];
        int end = sc[dl];
        float4 acc = make_float4(0.f, 0.f, 0.f, 0.f);
        for (int i = beg; i < end; i += 16) {
#pragma unroll
            for (int k = 0; k < 4; ++k) {
                int j = i + k * 4 + e4;
                bool ok = j < end;
                uint32_t s = srtd[ok ? j : i];         // LDS broadcast read
                float4 vv = x4[(size_t)s * (N_FEAT / 4) + q];
                float m = ok ? 1.0f : 0.0f;
                acc.x = fmaf(vv.x, m, acc.x);
                acc.y = fmaf(vv.y, m, acc.y);
                acc.z = fmaf(vv.z, m, acc.z);
                acc.w = fmaf(vv.w, m, acc.w);
            }
        }
        acc.x += __shfl_xor(acc.x, 8);  acc.y += __shfl_xor(acc.y, 8);
        acc.z += __shfl_xor(acc.z, 8);  acc.w += __shfl_xor(acc.w, 8);
        acc.x += __shfl_xor(acc.x, 16); acc.y += __shfl_xor(acc.y, 16);
        acc.z += __shfl_xor(acc.z, 16); acc.w += __shfl_xor(acc.w, 16);
        if (e4 == 0) {
            for (int i = 0; i < novf; ++i) {           // novf==0 normally
                uint32_t od = ovf_dst[i];
                if ((int)(od >> NPB_SHIFT) == b && (int)(od & (NPB - 1)) == dl) {
                    float4 vv = x4[(size_t)ovf_src[i] * (N_FEAT / 4) + q];
                    acc.x += vv.x; acc.y += vv.y; acc.z += vv.z; acc.w += vv.w;
                }
            }
            out4[(size_t)(n0 + dl) * (N_FEAT / 4) + q] = acc;
        }
    }
}

extern "C" void kernel_launch(void* const* d_in, const int* in_sizes, int n_in,
                              void* d_out, int out_size, void* d_ws, size_t ws_size,
                              hipStream_t stream) {
    const float* x   = (const float*)d_in[0];
    const int*   ei  = (const int*)d_in[1];
    float*       out = (float*)d_out;

    const int n_edges = in_sizes[1] / 2;
    const int n_nodes = in_sizes[0] / N_FEAT;
    const int* src = ei;
    const int* dst = ei + n_edges;

    const int nbins = (n_nodes + NPB - 1) >> NPB_SHIFT;

    // workspace layout
    size_t off_binstream = 0;
    size_t off_ovf_src   = off_binstream + (size_t)nbins * BINSLOT * sizeof(uint32_t);
    size_t off_ovf_dst   = off_ovf_src + (size_t)OVF_CAP * sizeof(uint32_t);
    size_t off_bincur    = off_ovf_dst + (size_t)OVF_CAP * sizeof(uint32_t);
    size_t off_ovf_cnt   = off_bincur + (size_t)nbins * sizeof(int);
    size_t ws_needed     = off_ovf_cnt + sizeof(int);

    if (nbins > MAX_BINS || n_nodes > (1 << 23) || ws_size < ws_needed) {
        // fallback: baseline atomic scatter (correct, ~177us)
        int threads = 256;
        zero_out<<<(out_size + threads - 1) / threads, threads, 0, stream>>>(out, out_size);
        long long total = (long long)n_edges * N_FEAT;
        mp_scatter_add<<<(int)((total + threads - 1) / threads), threads, 0, stream>>>(
            x, src, dst, out, n_edges);
        return;
    }

    char* ws = (char*)d_ws;
    uint32_t* binstream = (uint32_t*)(ws + off_binstream);
    uint32_t* ovf_src   = (uint32_t*)(ws + off_ovf_src);
    uint32_t* ovf_dst   = (uint32_t*)(ws + off_ovf_dst);
    int*      bincur    = (int*)(ws + off_bincur);
    int*      ovf_cnt   = (int*)(ws + off_ovf_cnt);

    init_bins<<<(nbins + 256) / 256, 256, 0, stream>>>(bincur, nbins, ovf_cnt);

    const int part_blocks = (n_edges + PART_CHUNK - 1) / PART_CHUNK;
    partition_bins<<<part_blocks, PART_THREADS, 0, stream>>>(
        src, dst, n_edges, bincur, binstream, ovf_src, ovf_dst, ovf_cnt, nbins);

    binsort_aggregate<<<nbins, FUSE_THREADS, 0, stream>>>(
        binstream, bincur, ovf_src, ovf_dst, ovf_cnt, x, out, n_nodes);
}

// Round 17
// 61.448 us; speedup vs baseline: 6.1234x; 1.0110x over previous
//
#include <hip/hip_runtime.h>
#include <stdint.h>

#define N_FEAT 32
#define NPB_SHIFT 8                   // 256 nodes per bin
#define NPB (1 << NPB_SHIFT)
#define MAX_BINS 512
#define BINSLOT 8192                  // fixed binstream slots per bin (avg load ~4096)
#define OVF_CAP 65536                 // overflow safety net (unused for this input)
#define PART_THREADS 1024
#define PART_CHUNK 3072               // edges per partition block (LDS-cached)
#define FUSE_THREADS 1024

// ---------- fallback path (baseline, known-correct, ~177us) ----------
__global__ void zero_out(float* __restrict__ out, int n) {
    int i = blockIdx.x * blockDim.x + threadIdx.x;
    if (i < n) out[i] = 0.0f;
}

__global__ void mp_scatter_add(const float* __restrict__ x,
                               const int* __restrict__ src,
                               const int* __restrict__ dst,
                               float* __restrict__ out,
                               int n_edges) {
    long long tid = (long long)blockIdx.x * blockDim.x + threadIdx.x;
    long long total = (long long)n_edges * N_FEAT;
    if (tid >= total) return;
    int e = (int)(tid >> 5);
    int f = (int)(tid & 31);
    atomicAdd(&out[(long long)dst[e] * N_FEAT + f],
              x[(long long)src[e] * N_FEAT + f]);
}

// ---------- fast path ----------
// R15 lesson: do NOT fuse dispatches via cooperative grid.sync() — grid-wide
// coherence across non-coherent XCD L2s degraded all caching (376us).
// R16 lesson: sort machinery is not the cost; the x-row gather is.

// K0: init per-bin cursors + overflow counter (ws is poisoned; must re-init).
__global__ void init_bins(int* __restrict__ bincur, int nbins,
                          int* __restrict__ ovf_cnt) {
    int t = blockIdx.x * blockDim.x + threadIdx.x;
    if (t < nbins) bincur[t] = t * BINSLOT;
    if (t == nbins) *ovf_cnt = 0;
}

// K1: partition edges into fixed-capacity bins (LDS-cached chunk; src/dst
// read from HBM exactly once).
__global__ void __launch_bounds__(PART_THREADS)
partition_bins(const int* __restrict__ src, const int* __restrict__ dst,
               int n_edges, int* __restrict__ bincur,
               uint32_t* __restrict__ binstream,
               uint32_t* __restrict__ ovf_src, uint32_t* __restrict__ ovf_dst,
               int* __restrict__ ovf_cnt, int nbins) {
    __shared__ uint32_t epack[PART_CHUNK];   // (src<<8)|dst_local
    __shared__ uint16_t ebin[PART_CHUNK];    // bin id
    __shared__ int cnt[MAX_BINS];
    __shared__ int base[MAX_BINS];
    const int beg = blockIdx.x * PART_CHUNK;
    const int end = min(beg + PART_CHUNK, n_edges);
    const int m = end - beg;

    for (int b = threadIdx.x; b < nbins; b += blockDim.x) cnt[b] = 0;
    __syncthreads();
    for (int i = threadIdx.x; i < m; i += blockDim.x) {
        int d = dst[beg + i];
        int s = src[beg + i];
        int b = d >> NPB_SHIFT;
        epack[i] = ((uint32_t)s << NPB_SHIFT) | (uint32_t)(d & (NPB - 1));
        ebin[i]  = (uint16_t)b;
        atomicAdd(&cnt[b], 1);               // LDS atomic
    }
    __syncthreads();
    for (int b = threadIdx.x; b < nbins; b += blockDim.x) {
        int c = cnt[b];
        base[b] = c ? atomicAdd(&bincur[b], c) : 0;   // one global atomic each
        cnt[b] = 0;                                   // becomes local cursor
    }
    __syncthreads();
    for (int i = threadIdx.x; i < m; i += blockDim.x) {
        int b = ebin[i];
        uint32_t e = epack[i];
        int p = base[b] + atomicAdd(&cnt[b], 1);      // LDS atomic
        if (p < (b + 1) * BINSLOT) {
            binstream[p] = e;                         // block-private segment
        } else {                                      // overflow net (never hit here)
            int o = atomicAdd(ovf_cnt, 1);
            if (o < OVF_CAP) {
                ovf_src[o] = e >> NPB_SHIFT;
                ovf_dst[o] = ((uint32_t)b << NPB_SHIFT) | (e & (NPB - 1));
            }
        }
    }
}

// K2 (FUSED sort+aggregate): one block per bin.
// R17a: gather = unmasked 16-wide main loop + 4-wide tail (over-issue 45%->12%).
// R17b: binstream staged via NON-TEMPORAL loads (one-shot stream; keeps x
//       rows hot in L2 for the gather).
__global__ void __launch_bounds__(FUSE_THREADS)
binsort_aggregate(const uint32_t* __restrict__ binstream,
                  const int* __restrict__ bincur,
                  const uint32_t* __restrict__ ovf_src,
                  const uint32_t* __restrict__ ovf_dst,
                  const int* __restrict__ ovf_cnt,
                  const float* __restrict__ x,
                  float* __restrict__ out, int n_nodes) {
    __shared__ uint32_t ebuf[BINSLOT];     // 32 KB: raw bin edges (single global read)
    __shared__ uint32_t srtd[BINSLOT];     // 32 KB: rank-sorted src ids
    __shared__ int hist[NPB];              // counts -> exclusive per-node start
    __shared__ int sc[NPB];                // inclusive per-node end
    __shared__ int lcur[NPB];
    __shared__ int wsum[4];                // per-wave scan totals
    const int b = blockIdx.x;
    const int n0 = b << NPB_SHIFT;
    const int nn = min(NPB, n_nodes - n0);
    const int binstart = b * BINSLOT;
    const int cnt = min(bincur[b] - binstart, BINSLOT);
    const int novf = *ovf_cnt;             // 0 in practice
    const int t = threadIdx.x;
    const int g  = t >> 5;                 // group 0..31
    const int l  = t & 31;
    const int e4 = l >> 3;                 // edge slot 0..3
    const int q  = l & 7;                  // feature quad 0..7
    const float4* __restrict__ x4 = (const float4*)x;
    float4* __restrict__ out4 = (float4*)out;

    if (t < NPB) { hist[t] = 0; lcur[t] = 0; }
    __syncthreads();
    for (int i = t; i < cnt; i += FUSE_THREADS) {
        uint32_t e = __builtin_nontemporal_load(&binstream[binstart + i]); // NT stream
        ebuf[i] = e;
        atomicAdd(&hist[e & (NPB - 1)], 1);
    }
    __syncthreads();

    // wave-shfl inclusive scan over hist[0..255] (4 full waves)
    int vin = 0, val = 0;
    if (t < NPB) {
        vin = hist[t];
        val = vin;
#pragma unroll
        for (int off = 1; off < 64; off <<= 1) {
            int u = __shfl_up(val, (unsigned)off, 64);
            if ((t & 63) >= off) val += u;
        }
        if ((t & 63) == 63) wsum[t >> 6] = val;
    }
    __syncthreads();
    if (t < NPB) {
        int w = t >> 6, prefix = 0;
#pragma unroll
        for (int k = 0; k < 3; ++k) if (k < w) prefix += wsum[k];
        val += prefix;
        sc[t] = val;                       // inclusive end
        hist[t] = val - vin;               // exclusive start
    }
    __syncthreads();

    for (int i = t; i < cnt; i += FUSE_THREADS) {
        uint32_t e = ebuf[i];              // LDS re-read (not global)
        int dl = (int)(e & (NPB - 1));
        int p = hist[dl] + atomicAdd(&lcur[dl], 1);
        srtd[p] = e >> NPB_SHIFT;          // src id
    }
    __syncthreads();

    for (int dl = g; dl < nn; dl += 32) {
        int beg = hist[dl];
        int end = sc[dl];
        float4 acc = make_float4(0.f, 0.f, 0.f, 0.f);
        int i = beg;
        // unmasked 16-wide main loop (no clamp, no mask FMAs)
        for (; i + 16 <= end; i += 16) {
#pragma unroll
            for (int k = 0; k < 4; ++k) {
                uint32_t s = srtd[i + k * 4 + e4];
                float4 vv = x4[(size_t)s * (N_FEAT / 4) + q];
                acc.x += vv.x; acc.y += vv.y; acc.z += vv.z; acc.w += vv.w;
            }
        }
        // 4-wide tail
        for (; i < end; i += 4) {
            int j = i + e4;
            bool ok = j < end;
            uint32_t s = srtd[ok ? j : i];
            float4 vv = x4[(size_t)s * (N_FEAT / 4) + q];
            float m = ok ? 1.0f : 0.0f;
            acc.x = fmaf(vv.x, m, acc.x);
            acc.y = fmaf(vv.y, m, acc.y);
            acc.z = fmaf(vv.z, m, acc.z);
            acc.w = fmaf(vv.w, m, acc.w);
        }
        acc.x += __shfl_xor(acc.x, 8);  acc.y += __shfl_xor(acc.y, 8);
        acc.z += __shfl_xor(acc.z, 8);  acc.w += __shfl_xor(acc.w, 8);
        acc.x += __shfl_xor(acc.x, 16); acc.y += __shfl_xor(acc.y, 16);
        acc.z += __shfl_xor(acc.z, 16); acc.w += __shfl_xor(acc.w, 16);
        if (e4 == 0) {
            for (int i2 = 0; i2 < novf; ++i2) {        // novf==0 normally
                uint32_t od = ovf_dst[i2];
                if ((int)(od >> NPB_SHIFT) == b && (int)(od & (NPB - 1)) == dl) {
                    float4 vv = x4[(size_t)ovf_src[i2] * (N_FEAT / 4) + q];
                    acc.x += vv.x; acc.y += vv.y; acc.z += vv.z; acc.w += vv.w;
                }
            }
            out4[(size_t)(n0 + dl) * (N_FEAT / 4) + q] = acc;
        }
    }
}

extern "C" void kernel_launch(void* const* d_in, const int* in_sizes, int n_in,
                              void* d_out, int out_size, void* d_ws, size_t ws_size,
                              hipStream_t stream) {
    const float* x   = (const float*)d_in[0];
    const int*   ei  = (const int*)d_in[1];
    float*       out = (float*)d_out;

    const int n_edges = in_sizes[1] / 2;
    const int n_nodes = in_sizes[0] / N_FEAT;
    const int* src = ei;
    const int* dst = ei + n_edges;

    const int nbins = (n_nodes + NPB - 1) >> NPB_SHIFT;

    // workspace layout
    size_t off_binstream = 0;
    size_t off_ovf_src   = off_binstream + (size_t)nbins * BINSLOT * sizeof(uint32_t);
    size_t off_ovf_dst   = off_ovf_src + (size_t)OVF_CAP * sizeof(uint32_t);
    size_t off_bincur    = off_ovf_dst + (size_t)OVF_CAP * sizeof(uint32_t);
    size_t off_ovf_cnt   = off_bincur + (size_t)nbins * sizeof(int);
    size_t ws_needed     = off_ovf_cnt + sizeof(int);

    if (nbins > MAX_BINS || n_nodes > (1 << 23) || ws_size < ws_needed) {
        // fallback: baseline atomic scatter (correct, ~177us)
        int threads = 256;
        zero_out<<<(out_size + threads - 1) / threads, threads, 0, stream>>>(out, out_size);
        long long total = (long long)n_edges * N_FEAT;
        mp_scatter_add<<<(int)((total + threads - 1) / threads), threads, 0, stream>>>(
            x, src, dst, out, n_edges);
        return;
    }

    char* ws = (char*)d_ws;
    uint32_t* binstream = (uint32_t*)(ws + off_binstream);
    uint32_t* ovf_src   = (uint32_t*)(ws + off_ovf_src);
    uint32_t* ovf_dst   = (uint32_t*)(ws + off_ovf_dst);
    int*      bincur    = (int*)(ws + off_bincur);
    int*      ovf_cnt   = (int*)(ws + off_ovf_cnt);

    init_bins<<<(nbins + 256) / 256, 256, 0, stream>>>(bincur, nbins, ovf_cnt);

    const int part_blocks = (n_edges + PART_CHUNK - 1) / PART_CHUNK;
    partition_bins<<<part_blocks, PART_THREADS, 0, stream>>>(
        src, dst, n_edges, bincur, binstream, ovf_src, ovf_dst, ovf_cnt, nbins);

    binsort_aggregate<<<nbins, FUSE_THREADS, 0, stream>>>(
        binstream, bincur, ovf_src, ovf_dst, ovf_cnt, x, out, n_nodes);
}